// Round 7
// baseline (31.358 us; speedup 1.0000x reference)
//
#include <hip/hip_runtime.h>

typedef _Float16 f16;
typedef _Float16 f16x4 __attribute__((ext_vector_type(4)));
typedef _Float16 f16x8 __attribute__((ext_vector_type(8)));
typedef float f32x16 __attribute__((ext_vector_type(16)));
typedef float f32x4 __attribute__((ext_vector_type(4)));

#define APITCH 264       // f16 units; 528 B pitch
#define WREG 67584       // f16 units per ws region: 65536 + 2048 pad (OOB prefetch)

// ============================================================================
// prep: build fragment-major f16 B-operands in ws (identical to round 6).
//   W1h/W1l[f*512 + l*8 + j] = f16 hi/lo of 256*R[32g + (l&31)][16*ks16 + 8*(l>>5) + j]
//   W2h    [f*512 + l*8 + j] = f16 of        R[16*ks16 + 8*(l>>5) + j][32g + (l&31)]
// ============================================================================
__global__ __launch_bounds__(1024) void prep_kernel(const float* __restrict__ R,
                                                    f16* __restrict__ ws) {
  __shared__ float Lrs[32][260];
  const int g = blockIdx.x;   // 0..7
  const int t = threadIdx.x;  // 0..1023
  f16* W1h = ws;
  f16* W1l = ws + WREG;
  f16* W2h = ws + 2 * WREG;

  #pragma unroll
  for (int it = 0; it < 2; ++it) {
    int c = it * 1024 + t;
    int row = c >> 6, c4 = (c & 63) * 4;
    f32x4 v = *(const f32x4*)&R[(long)(32 * g + row) * 256 + c4];
    *(f32x4*)&Lrs[row][c4] = v;
  }
  __syncthreads();

  {
    int f_loc = t >> 6, l = t & 63;
    int k0 = 16 * f_loc + 8 * (l >> 5);
    const float* src = &Lrs[l & 31][k0];
    f16x8 h, lo;
    #pragma unroll
    for (int j = 0; j < 8; ++j) {
      float v = src[j] * 256.0f;
      f16 hh = (f16)v;
      h[j] = hh;
      lo[j] = (f16)(v - (float)hh);
    }
    long o = (long)(g * 16 + f_loc) * 512 + l * 8;
    *(f16x8*)(W1h + o) = h;
    *(f16x8*)(W1l + o) = lo;
  }

  {
    int gp = t >> 7, e = (t >> 6) & 1, l = t & 63;
    int lr0 = 16 * e + 8 * (l >> 5);
    int col = 32 * gp + (l & 31);
    f16x8 h;
    #pragma unroll
    for (int j = 0; j < 8; ++j) h[j] = (f16)Lrs[lr0 + j][col];
    long o = (long)(gp * 16 + 2 * g + e) * 512 + l * 8;
    *(f16x8*)(W2h + o) = h;
  }
}

// ============================================================================
// main: 256 blocks x 512 threads (8 waves), 64 rows/block.
// Wave tile 64x32 (m=2): halves per-output B-fragment traffic vs 32-row tiles.
// Barrier-free k-loops; depth-4 prefetch; B preloads issued before norm phase.
// ============================================================================
__global__ __launch_bounds__(512, 1) void tq_main(
    const float* __restrict__ X, const float* __restrict__ CB,
    const f16* __restrict__ ws, float* __restrict__ OUT) {
  __shared__ f16 A1h[64][APITCH];   // aliased as Qs after mm1
  __shared__ f16 A1l[64][APITCH];
  __shared__ float s2s[64];

  const int tid = threadIdx.x;
  const int lane = tid & 63;
  const int wv = tid >> 6;       // 0..7 = 32-col group
  const int lrow = lane & 31;
  const int kg = lane >> 5;
  const long row0 = (long)blockIdx.x * 64;

  const f16* W1h = ws;
  const f16* W1l = ws + WREG;
  const f16* W2h = ws + 2 * WREG;

  // ---- issue x loads (64 rows; 8 threads/row, 32 consecutive floats each) ----
  const int r = tid >> 3, q = tid & 7;
  const float* xp = X + (row0 + r) * 256 + q * 32;
  float xa[32];
  #pragma unroll
  for (int i = 0; i < 8; ++i) {
    f32x4 v = ((const f32x4*)xp)[i];
    xa[4 * i] = v.x; xa[4 * i + 1] = v.y; xa[4 * i + 2] = v.z; xa[4 * i + 3] = v.w;
  }

  // ---- issue mm1 depth-4 B preloads NOW (independent of x); latency hides
  //      under norm + split ----
  const f16* W1hp = W1h + (long)(wv * 16) * 512 + lane * 8;
  const f16* W1lp = W1l + (long)(wv * 16) * 512 + lane * 8;
  f16x8 bh0 = *(const f16x8*)(W1hp);
  f16x8 bl0 = *(const f16x8*)(W1lp);
  f16x8 bh1 = *(const f16x8*)(W1hp + 512);
  f16x8 bl1 = *(const f16x8*)(W1lp + 512);
  f16x8 bh2 = *(const f16x8*)(W1hp + 1024);
  f16x8 bl2 = *(const f16x8*)(W1lp + 1024);
  f16x8 bh3 = *(const f16x8*)(W1hp + 1536);
  f16x8 bl3 = *(const f16x8*)(W1lp + 1536);

  // ---- row norm via shfl (8 threads/row) ----
  float ss = 0.f;
  #pragma unroll
  for (int i = 0; i < 32; ++i) ss += xa[i] * xa[i];
  ss += __shfl_xor(ss, 4, 8);
  ss += __shfl_xor(ss, 2, 8);
  ss += __shfl_xor(ss, 1, 8);
  float nrm = fmaxf(sqrtf(ss), 1e-8f);
  float s1f = 4096.0f / nrm;         // y_raw = 65536 * y_scaled
  if (q == 0) s2s[r] = nrm * 0.0625f;

  // ---- split A = x*s1 into f16 hi/lo -> LDS ----
  #pragma unroll
  for (int c8 = 0; c8 < 4; ++c8) {
    f16x8 h, l;
    #pragma unroll
    for (int j = 0; j < 8; ++j) {
      float a = xa[c8 * 8 + j] * s1f;
      f16 hh = (f16)a;
      h[j] = hh;
      l[j] = (f16)(a - (float)hh);
    }
    *(f16x8*)&A1h[r][q * 32 + c8 * 8] = h;
    *(f16x8*)&A1l[r][q * 32 + c8 * 8] = l;
  }
  __syncthreads();

  // ---- mm1: 64x32 wave tile, 4 acc chains, depth-4 prefetch, no barriers ----
  f32x16 zv;
  #pragma unroll
  for (int i = 0; i < 16; ++i) zv[i] = 0.0f;
  f32x16 accH0 = zv, accL0 = zv, accH1 = zv, accL1 = zv;

#define MM1_STAGE(BH, BL, KS)                                                   \
  {                                                                             \
    const int k0 = (KS) * 16 + kg * 8;                                          \
    f16x8 ah0 = *(const f16x8*)&A1h[lrow][k0];                                  \
    f16x8 al0 = *(const f16x8*)&A1l[lrow][k0];                                  \
    f16x8 ah1 = *(const f16x8*)&A1h[32 + lrow][k0];                             \
    f16x8 al1 = *(const f16x8*)&A1l[32 + lrow][k0];                             \
    accH0 = __builtin_amdgcn_mfma_f32_32x32x16_f16(ah0, BH, accH0, 0, 0, 0);    \
    accL0 = __builtin_amdgcn_mfma_f32_32x32x16_f16(al0, BH, accL0, 0, 0, 0);    \
    accH1 = __builtin_amdgcn_mfma_f32_32x32x16_f16(ah1, BH, accH1, 0, 0, 0);    \
    accL1 = __builtin_amdgcn_mfma_f32_32x32x16_f16(al1, BH, accL1, 0, 0, 0);    \
    accH0 = __builtin_amdgcn_mfma_f32_32x32x16_f16(ah0, BL, accH0, 0, 0, 0);    \
    accL0 = __builtin_amdgcn_mfma_f32_32x32x16_f16(al0, BL, accL0, 0, 0, 0);    \
    accH1 = __builtin_amdgcn_mfma_f32_32x32x16_f16(ah1, BL, accH1, 0, 0, 0);    \
    accL1 = __builtin_amdgcn_mfma_f32_32x32x16_f16(al1, BL, accL1, 0, 0, 0);    \
    BH = *(const f16x8*)(W1hp + ((KS) + 4) * 512);                              \
    BL = *(const f16x8*)(W1lp + ((KS) + 4) * 512);                              \
  }

  #pragma unroll
  for (int ksb = 0; ksb < 16; ksb += 4) {
    MM1_STAGE(bh0, bl0, ksb)
    MM1_STAGE(bh1, bl1, ksb + 1)
    MM1_STAGE(bh2, bl2, ksb + 2)
    MM1_STAGE(bh3, bl3, ksb + 3)
  }
#undef MM1_STAGE

  f32x16 acc0, acc1;
  #pragma unroll
  for (int i = 0; i < 16; ++i) { acc0[i] = accH0[i] + accL0[i]; acc1[i] = accH1[i] + accL1[i]; }

  // ---- issue mm2 depth-4 preloads (latency hides under quantize) ----
  const f16* W2p = W2h + (long)(wv * 16) * 512 + lane * 8;
  f16x8 c0 = *(const f16x8*)(W2p);
  f16x8 c1 = *(const f16x8*)(W2p + 512);
  f16x8 c2 = *(const f16x8*)(W2p + 1024);
  f16x8 c3 = *(const f16x8*)(W2p + 1536);

  __syncthreads();   // all waves done reading A1h/A1l (Qs aliases A1h)

  // ---- codebook ----
  float cbf[16];
  #pragma unroll
  for (int i = 0; i < 16; ++i) cbf[i] = CB[i];
  float M[15];
  #pragma unroll
  for (int t = 0; t < 15; ++t) M[t] = 65536.0f * (0.5f * (cbf[t] + cbf[t + 1]));
  unsigned int cpk[8];
  #pragma unroll
  for (int i = 0; i < 8; ++i) {
    unsigned short lb = __builtin_bit_cast(unsigned short, (f16)cbf[2 * i]);
    unsigned short hb = __builtin_bit_cast(unsigned short, (f16)cbf[2 * i + 1]);
    cpk[i] = ((unsigned int)hb << 16) | (unsigned int)lb;
  }

  // ---- quantize -> Qs (aliases A1h): id = 8b3+4b2+2b1+b0 ----
  f16 (*Qs)[APITCH] = A1h;
  #pragma unroll
  for (int m = 0; m < 2; ++m) {
    const f32x16& am = m ? acc1 : acc0;
    #pragma unroll
    for (int rr = 0; rr < 16; ++rr) {
      float y = am[rr];
      int row = 32 * m + 4 * kg + (rr & 3) + 8 * (rr >> 2);
      int kk = 32 * wv + lrow;
      bool b3 = y > M[7];
      float m2 = b3 ? M[11] : M[3];
      bool b2 = y > m2;
      float m1 = b3 ? (b2 ? M[13] : M[9]) : (b2 ? M[5] : M[1]);
      bool b1 = y > m1;
      float m0 = b1 ? (b3 ? (b2 ? M[14] : M[10]) : (b2 ? M[6] : M[2]))
                    : (b3 ? (b2 ? M[12] : M[8]) : (b2 ? M[4] : M[0]));
      bool b0 = y > m0;
      unsigned int pp = b3 ? (b2 ? (b1 ? cpk[7] : cpk[6]) : (b1 ? cpk[5] : cpk[4]))
                           : (b2 ? (b1 ? cpk[3] : cpk[2]) : (b1 ? cpk[1] : cpk[0]));
      unsigned short qb = (unsigned short)(b0 ? (pp >> 16) : (pp & 0xFFFFu));
      Qs[row][kk] = __builtin_bit_cast(f16, qb);
    }
  }
  __syncthreads();

  // ---- mm2: 2 acc chains, depth-4 rotation, no barriers ----
  f32x16 acc2_0 = zv, acc2_1 = zv;

#define MM2_STAGE(CS, KS)                                                       \
  {                                                                             \
    const int k0 = (KS) * 16 + kg * 8;                                          \
    f16x8 qa0 = *(const f16x8*)&Qs[lrow][k0];                                   \
    f16x8 qa1 = *(const f16x8*)&Qs[32 + lrow][k0];                              \
    acc2_0 = __builtin_amdgcn_mfma_f32_32x32x16_f16(qa0, CS, acc2_0, 0, 0, 0);  \
    acc2_1 = __builtin_amdgcn_mfma_f32_32x32x16_f16(qa1, CS, acc2_1, 0, 0, 0);  \
    CS = *(const f16x8*)(W2p + ((KS) + 4) * 512);                               \
  }

  #pragma unroll
  for (int ksb = 0; ksb < 16; ksb += 4) {
    MM2_STAGE(c0, ksb)
    MM2_STAGE(c1, ksb + 1)
    MM2_STAGE(c2, ksb + 2)
    MM2_STAGE(c3, ksb + 3)
  }
#undef MM2_STAGE

  // ---- epilogue ----
  #pragma unroll
  for (int m = 0; m < 2; ++m) {
    const f32x16& am = m ? acc2_1 : acc2_0;
    #pragma unroll
    for (int rr = 0; rr < 16; ++rr) {
      int row = 32 * m + 4 * kg + (rr & 3) + 8 * (rr >> 2);
      int col = 32 * wv + lrow;
      OUT[(row0 + row) * 256 + col] = am[rr] * s2s[row];
    }
  }
}

// ============================================================================
// fallback (round-4 kernel, passed at 36 us) if ws is too small
// ============================================================================
#define FB_APITCH 264
#define FB_B1PITCH 40
#define FB_B2PITCH 264

__global__ __launch_bounds__(256, 1) void tq_main_fb(
    const float* __restrict__ X, const float* __restrict__ R,
    const float* __restrict__ CB, float* __restrict__ OUT) {
  __shared__ f16 A1h[64][FB_APITCH];
  __shared__ f16 A1l[64][FB_APITCH];
  __shared__ f16 Qs[64][FB_APITCH];
  __shared__ f32x4 Braw[2624];
  __shared__ float pn[4][64];
  __shared__ float s1s[64];
  __shared__ float s2s[64];

  f16 (*B1h)[FB_B1PITCH] = (f16(*)[FB_B1PITCH])Braw;
  f16 (*B1l)[FB_B1PITCH] = (f16(*)[FB_B1PITCH])((char*)Braw + 20480);
  f16 (*B2h)[FB_B2PITCH] = (f16(*)[FB_B2PITCH])Braw;

  const int tid = threadIdx.x;
  const int lane = tid & 63;
  const int wv = tid >> 6;
  const int lrow = lane & 31;
  const int kg = lane >> 5;
  const long row0 = (long)blockIdx.x * 64;

  float cbf[16];
  #pragma unroll
  for (int i = 0; i < 16; ++i) cbf[i] = CB[i];
  float M[15];
  #pragma unroll
  for (int t = 0; t < 15; ++t) M[t] = 65536.0f * (0.5f * (cbf[t] + cbf[t + 1]));
  unsigned int cpk[8];
  #pragma unroll
  for (int i = 0; i < 8; ++i) {
    unsigned short lb = __builtin_bit_cast(unsigned short, (f16)cbf[2 * i]);
    unsigned short hb = __builtin_bit_cast(unsigned short, (f16)cbf[2 * i + 1]);
    cpk[i] = ((unsigned int)hb << 16) | (unsigned int)lb;
  }

  const int xrow = tid >> 2, xq = tid & 3;
  const float* xp = X + (row0 + xrow) * 256 + xq * 64;
  float xa[64];
  #pragma unroll
  for (int i = 0; i < 16; ++i) {
    f32x4 v = ((const f32x4*)xp)[i];
    xa[4 * i] = v.x; xa[4 * i + 1] = v.y; xa[4 * i + 2] = v.z; xa[4 * i + 3] = v.w;
  }
  float ss = 0.f;
  #pragma unroll
  for (int i = 0; i < 64; ++i) ss += xa[i] * xa[i];
  pn[xq][xrow] = ss;
  __syncthreads();
  if (tid < 64) {
    float s = pn[0][tid] + pn[1][tid] + pn[2][tid] + pn[3][tid];
    float nrm = fmaxf(sqrtf(s), 1e-8f);
    s1s[tid] = 4096.0f / nrm;
    s2s[tid] = nrm * 0.0625f;
  }
  __syncthreads();

  {
    float s1f = s1s[xrow];
    #pragma unroll
    for (int c8 = 0; c8 < 8; ++c8) {
      f16x8 h, l;
      #pragma unroll
      for (int j = 0; j < 8; ++j) {
        float a = xa[c8 * 8 + j] * s1f;
        f16 hh = (f16)a;
        h[j] = hh;
        l[j] = (f16)(a - (float)hh);
      }
      *(f16x8*)&A1h[xrow][xq * 64 + c8 * 8] = h;
      *(f16x8*)&A1l[xrow][xq * 64 + c8 * 8] = l;
    }
  }

  f32x4 pf[8];
  #pragma unroll
  for (int q = 0; q < 8; ++q) {
    int c = q * 256 + tid;
    pf[q] = *(const f32x4*)&R[(long)(c >> 3) * 256 + ((c & 7) * 4)];
  }

  f32x16 zv;
  #pragma unroll
  for (int i = 0; i < 16; ++i) zv[i] = 0.0f;
  f32x16 acc[2][2];
  acc[0][0] = zv; acc[0][1] = zv; acc[1][0] = zv; acc[1][1] = zv;

  for (int kp = 0; kp < 8; ++kp) {
    __syncthreads();
    #pragma unroll
    for (int q = 0; q < 8; ++q) {
      int c = q * 256 + tid;
      int n = c >> 3, k4 = (c & 7) * 4;
      f16x4 h, l;
      #pragma unroll
      for (int j = 0; j < 4; ++j) {
        float sv = pf[q][j] * 256.0f;
        f16 hh = (f16)sv;
        h[j] = hh;
        l[j] = (f16)(sv - (float)hh);
      }
      *(f16x4*)&B1h[n][k4] = h;
      *(f16x4*)&B1l[n][k4] = l;
    }
    __syncthreads();
    if (kp < 7) {
      #pragma unroll
      for (int q = 0; q < 8; ++q) {
        int c = q * 256 + tid;
        pf[q] = *(const f32x4*)&R[(long)(c >> 3) * 256 + (kp + 1) * 32 + ((c & 7) * 4)];
      }
    }
    #pragma unroll
    for (int ks = 0; ks < 2; ++ks) {
      const int k0 = kp * 32 + ks * 16 + kg * 8;
      const int lk = ks * 16 + kg * 8;
      f16x8 ah[2], al[2], bhf[2], blf[2];
      #pragma unroll
      for (int m = 0; m < 2; ++m) {
        ah[m] = *(const f16x8*)&A1h[32 * m + lrow][k0];
        al[m] = *(const f16x8*)&A1l[32 * m + lrow][k0];
      }
      #pragma unroll
      for (int n = 0; n < 2; ++n) {
        int col = 64 * wv + 32 * n + lrow;
        bhf[n] = *(const f16x8*)&B1h[col][lk];
        blf[n] = *(const f16x8*)&B1l[col][lk];
      }
      #pragma unroll
      for (int m = 0; m < 2; ++m)
        #pragma unroll
        for (int n = 0; n < 2; ++n) {
          acc[m][n] = __builtin_amdgcn_mfma_f32_32x32x16_f16(ah[m], bhf[n], acc[m][n], 0, 0, 0);
          acc[m][n] = __builtin_amdgcn_mfma_f32_32x32x16_f16(al[m], bhf[n], acc[m][n], 0, 0, 0);
          acc[m][n] = __builtin_amdgcn_mfma_f32_32x32x16_f16(ah[m], blf[n], acc[m][n], 0, 0, 0);
          acc[m][n] = __builtin_amdgcn_mfma_f32_32x32x16_f16(al[m], blf[n], acc[m][n], 0, 0, 0);
        }
    }
  }

  #pragma unroll
  for (int q = 0; q < 8; ++q) {
    int c = q * 256 + tid;
    pf[q] = *(const f32x4*)&R[(long)(c >> 6) * 256 + ((c & 63) * 4)];
  }

  #pragma unroll
  for (int m = 0; m < 2; ++m)
    #pragma unroll
    for (int n = 0; n < 2; ++n)
      #pragma unroll
      for (int rr = 0; rr < 16; ++rr) {
        float y = acc[m][n][rr];
        int row = 32 * m + 4 * kg + (rr & 3) + 8 * (rr >> 2);
        int kk = 64 * wv + 32 * n + lrow;
        bool b3 = y > M[7];
        float m2 = b3 ? M[11] : M[3];
        bool b2 = y > m2;
        float m1 = b3 ? (b2 ? M[13] : M[9]) : (b2 ? M[5] : M[1]);
        bool b1 = y > m1;
        float m0 = b1 ? (b3 ? (b2 ? M[14] : M[10]) : (b2 ? M[6] : M[2]))
                      : (b3 ? (b2 ? M[12] : M[8]) : (b2 ? M[4] : M[0]));
        bool b0 = y > m0;
        unsigned int pp = b3 ? (b2 ? (b1 ? cpk[7] : cpk[6]) : (b1 ? cpk[5] : cpk[4]))
                             : (b2 ? (b1 ? cpk[3] : cpk[2]) : (b1 ? cpk[1] : cpk[0]));
        unsigned short qb = (unsigned short)(b0 ? (pp >> 16) : (pp & 0xFFFFu));
        Qs[row][kk] = __builtin_bit_cast(f16, qb);
      }
  __syncthreads();

  f32x16 acc2[2][2];
  acc2[0][0] = zv; acc2[0][1] = zv; acc2[1][0] = zv; acc2[1][1] = zv;

  for (int kp = 0; kp < 8; ++kp) {
    if (kp) __syncthreads();
    #pragma unroll
    for (int q = 0; q < 8; ++q) {
      int c = q * 256 + tid;
      int k = c >> 6, n4 = (c & 63) * 4;
      f16x4 h;
      #pragma unroll
      for (int j = 0; j < 4; ++j) h[j] = (f16)pf[q][j];
      *(f16x4*)&B2h[k][n4] = h;
    }
    __syncthreads();
    if (kp < 7) {
      #pragma unroll
      for (int q = 0; q < 8; ++q) {
        int c = q * 256 + tid;
        pf[q] = *(const f32x4*)&R[(long)((kp + 1) * 32 + (c >> 6)) * 256 + ((c & 63) * 4)];
      }
    }
    #pragma unroll
    for (int ks = 0; ks < 2; ++ks) {
      const int k0 = kp * 32 + ks * 16 + kg * 8;
      const int lk = ks * 16 + kg * 8;
      f16x8 qa[2], bb[2];
      #pragma unroll
      for (int m = 0; m < 2; ++m) qa[m] = *(const f16x8*)&Qs[32 * m + lrow][k0];
      #pragma unroll
      for (int n = 0; n < 2; ++n) {
        int colg = 64 * wv + 32 * n + lrow;
        #pragma unroll
        for (int j = 0; j < 8; ++j) bb[n][j] = B2h[lk + j][colg];
      }
      #pragma unroll
      for (int m = 0; m < 2; ++m)
        #pragma unroll
        for (int n = 0; n < 2; ++n)
          acc2[m][n] = __builtin_amdgcn_mfma_f32_32x32x16_f16(qa[m], bb[n], acc2[m][n], 0, 0, 0);
    }
  }

  #pragma unroll
  for (int m = 0; m < 2; ++m)
    #pragma unroll
    for (int n = 0; n < 2; ++n)
      #pragma unroll
      for (int rr = 0; rr < 16; ++rr) {
        int row = 32 * m + 4 * kg + (rr & 3) + 8 * (rr >> 2);
        int col = 64 * wv + 32 * n + lrow;
        OUT[(row0 + row) * 256 + col] = acc2[m][n][rr] * s2s[row];
      }
}

extern "C" void kernel_launch(void* const* d_in, const int* in_sizes, int n_in,
                              void* d_out, int out_size, void* d_ws, size_t ws_size,
                              hipStream_t stream) {
  const float* X = (const float*)d_in[0];
  const float* R = (const float*)d_in[1];
  const float* CB = (const float*)d_in[2];
  float* OUT = (float*)d_out;
  const int nrows = in_sizes[0] / 256;  // 16384

  if (ws_size >= (size_t)3 * WREG * sizeof(f16)) {
    f16* ws = (f16*)d_ws;
    prep_kernel<<<8, 1024, 0, stream>>>(R, ws);
    tq_main<<<nrows / 64, 512, 0, stream>>>(X, CB, ws, OUT);
  } else {
    tq_main_fb<<<nrows / 64, 256, 0, stream>>>(X, R, CB, OUT);
  }
}

// Round 8
// 26.115 us; speedup vs baseline: 1.2008x; 1.2008x over previous
//
#include <hip/hip_runtime.h>

typedef _Float16 f16;
typedef _Float16 f16x4 __attribute__((ext_vector_type(4)));
typedef _Float16 f16x8 __attribute__((ext_vector_type(8)));
typedef float f32x16 __attribute__((ext_vector_type(16)));
typedef float f32x4 __attribute__((ext_vector_type(4)));

#define APITCH 264       // f16 units; 528 B pitch
#define WREG 67584       // f16 units per ws region: 65536 + 2048 pad (OOB prefetch)

// ============================================================================
// prep: build fragment-major f16 B-operands in ws. Same fragment spec:
//   W1h/W1l[f*512 + l*8 + j] = f16 hi/lo of 256*R[32g + (l&31)][16*ks16 + 8*(l>>5) + j]
//   W2h    [f*512 + l*8 + j] = f16 of        R[16*ks16 + 8*(l>>5) + j][32g + (l&31)]
// Now 32 blocks: block (g = b>>2, h = b&3) stages panel g (rows 32g..32g+31),
// writes W1 frags f_loc in {4h..4h+3} and W2 frags for gp in {2h, 2h+1}.
// Coverage: W1 (g, f_loc): 8x4 blocks x 4 = all 128 frags once. W2 frag
// gp*16 + 2g + e: over (g,h,e) -> all 128 once.
// ============================================================================
__global__ __launch_bounds__(512) void prep_kernel(const float* __restrict__ R,
                                                   f16* __restrict__ ws) {
  __shared__ float Lrs[32][260];
  const int b = blockIdx.x;   // 0..31
  const int g = b >> 2, h = b & 3;
  const int t = threadIdx.x;  // 0..511
  f16* W1h = ws;
  f16* W1l = ws + WREG;
  f16* W2h = ws + 2 * WREG;

  #pragma unroll
  for (int it = 0; it < 4; ++it) {
    int c = it * 512 + t;             // 0..2047
    int row = c >> 6, c4 = (c & 63) * 4;
    f32x4 v = *(const f32x4*)&R[(long)(32 * g + row) * 256 + c4];
    *(f32x4*)&Lrs[row][c4] = v;
  }
  __syncthreads();

  if (t < 256) {
    // ---- W1h/W1l: f_loc = 4h + (t>>6), l = t&63 ----
    int f_loc = 4 * h + (t >> 6), l = t & 63;
    int k0 = 16 * f_loc + 8 * (l >> 5);
    const float* src = &Lrs[l & 31][k0];
    f16x8 hi, lo;
    #pragma unroll
    for (int j = 0; j < 8; ++j) {
      float v = src[j] * 256.0f;
      f16 hh = (f16)v;
      hi[j] = hh;
      lo[j] = (f16)(v - (float)hh);
    }
    long o = (long)(g * 16 + f_loc) * 512 + l * 8;
    *(f16x8*)(W1h + o) = hi;
    *(f16x8*)(W1l + o) = lo;
  } else {
    // ---- W2h: u = t-256: gp = 2h + (u>>7), e = (u>>6)&1, l = u&63 ----
    int u = t - 256;
    int gp = 2 * h + (u >> 7), e = (u >> 6) & 1, l = u & 63;
    int lr0 = 16 * e + 8 * (l >> 5);
    int col = 32 * gp + (l & 31);
    f16x8 hv;
    #pragma unroll
    for (int j = 0; j < 8; ++j) hv[j] = (f16)Lrs[lr0 + j][col];
    long o = (long)(gp * 16 + 2 * g + e) * 512 + l * 8;
    *(f16x8*)(W2h + o) = hv;
  }
}

// ============================================================================
// main: 512 blocks x 512 threads (8 waves), 32 rows/block, wave tile 32x32.
// Barrier-free k-loops; depth-2 prefetch; 3-term f16 split in mm1;
// codebook loaded at kernel start (hides cold-load latency).
// ============================================================================
__global__ __launch_bounds__(512, 4) void tq_main(
    const float* __restrict__ X, const float* __restrict__ CB,
    const f16* __restrict__ ws, float* __restrict__ OUT) {
  __shared__ f16 A1h[32][APITCH];   // aliased as Qs after mm1
  __shared__ f16 A1l[32][APITCH];
  __shared__ float s2s[32];

  const int tid = threadIdx.x;
  const int lane = tid & 63;
  const int wv = tid >> 6;       // 0..7 = 32-col group
  const int lrow = lane & 31;
  const int kg = lane >> 5;
  const long row0 = (long)blockIdx.x * 32;

  const f16* W1h = ws;
  const f16* W1l = ws + WREG;
  const f16* W2h = ws + 2 * WREG;

  // ---- issue x loads first (HBM priority) ----
  const int r = tid >> 4, q = tid & 15;
  const float* xp = X + (row0 + r) * 256 + q * 16;
  float xa[16];
  #pragma unroll
  for (int i = 0; i < 4; ++i) {
    f32x4 v = ((const f32x4*)xp)[i];
    xa[4 * i] = v.x; xa[4 * i + 1] = v.y; xa[4 * i + 2] = v.z; xa[4 * i + 3] = v.w;
  }

  // ---- codebook load issued early (latency hides under norm/split/mm1) ----
  float cbf[16];
  #pragma unroll
  for (int i = 0; i < 16; ++i) cbf[i] = CB[i];

  // ---- wave-local norm via shfl (16 threads/row) ----
  float ss = 0.f;
  #pragma unroll
  for (int i = 0; i < 16; ++i) ss += xa[i] * xa[i];
  ss += __shfl_xor(ss, 8, 16);
  ss += __shfl_xor(ss, 4, 16);
  ss += __shfl_xor(ss, 2, 16);
  ss += __shfl_xor(ss, 1, 16);
  float nrm = fmaxf(sqrtf(ss), 1e-8f);
  float s1f = 4096.0f / nrm;         // y_raw = 65536 * y_scaled
  if (q == 0) s2s[r] = nrm * 0.0625f;

  // ---- split A = x*s1 into f16 hi/lo -> LDS ----
  #pragma unroll
  for (int c8 = 0; c8 < 2; ++c8) {
    f16x8 h, l;
    #pragma unroll
    for (int j = 0; j < 8; ++j) {
      float a = xa[c8 * 8 + j] * s1f;
      f16 hh = (f16)a;
      h[j] = hh;
      l[j] = (f16)(a - (float)hh);
    }
    *(f16x8*)&A1h[r][q * 16 + c8 * 8] = h;
    *(f16x8*)&A1l[r][q * 16 + c8 * 8] = l;
  }
  __syncthreads();

  // ---- mm1: depth-2 prefetch, dual acc chains, 3-term split, no barriers ----
  const f16* W1hp = W1h + (long)(wv * 16) * 512 + lane * 8;
  const f16* W1lp = W1l + (long)(wv * 16) * 512 + lane * 8;
  f16x8 bh0 = *(const f16x8*)(W1hp);
  f16x8 bl0 = *(const f16x8*)(W1lp);
  f16x8 bh1 = *(const f16x8*)(W1hp + 512);
  f16x8 bl1 = *(const f16x8*)(W1lp + 512);

  f32x16 zv;
  #pragma unroll
  for (int i = 0; i < 16; ++i) zv[i] = 0.0f;
  f32x16 accH = zv, accL = zv;

  #pragma unroll
  for (int ks = 0; ks < 16; ks += 2) {
    {
      const int k0 = ks * 16 + kg * 8;
      f16x8 ah = *(const f16x8*)&A1h[lrow][k0];
      f16x8 al = *(const f16x8*)&A1l[lrow][k0];
      accH = __builtin_amdgcn_mfma_f32_32x32x16_f16(ah, bh0, accH, 0, 0, 0);
      accL = __builtin_amdgcn_mfma_f32_32x32x16_f16(al, bh0, accL, 0, 0, 0);
      accH = __builtin_amdgcn_mfma_f32_32x32x16_f16(ah, bl0, accH, 0, 0, 0);
      bh0 = *(const f16x8*)(W1hp + (ks + 2) * 512);   // ks=14 -> pad region
      bl0 = *(const f16x8*)(W1lp + (ks + 2) * 512);
    }
    {
      const int k0 = (ks + 1) * 16 + kg * 8;
      f16x8 ah = *(const f16x8*)&A1h[lrow][k0];
      f16x8 al = *(const f16x8*)&A1l[lrow][k0];
      accH = __builtin_amdgcn_mfma_f32_32x32x16_f16(ah, bh1, accH, 0, 0, 0);
      accL = __builtin_amdgcn_mfma_f32_32x32x16_f16(al, bh1, accL, 0, 0, 0);
      accH = __builtin_amdgcn_mfma_f32_32x32x16_f16(ah, bl1, accH, 0, 0, 0);
      bh1 = *(const f16x8*)(W1hp + (ks + 3) * 512);
      bl1 = *(const f16x8*)(W1lp + (ks + 3) * 512);
    }
  }

  // ---- issue mm2 depth-4 preloads (latency hides under quantize) ----
  const f16* W2p = W2h + (long)(wv * 16) * 512 + lane * 8;
  f16x8 c0 = *(const f16x8*)(W2p);
  f16x8 c1 = *(const f16x8*)(W2p + 512);
  f16x8 c2 = *(const f16x8*)(W2p + 1024);
  f16x8 c3 = *(const f16x8*)(W2p + 1536);

  // ---- midpoints / packed codebook (cbf already resident) ----
  float M[15];
  #pragma unroll
  for (int t = 0; t < 15; ++t) M[t] = 65536.0f * (0.5f * (cbf[t] + cbf[t + 1]));
  unsigned int cpk[8];
  #pragma unroll
  for (int i = 0; i < 8; ++i) {
    unsigned short lb = __builtin_bit_cast(unsigned short, (f16)cbf[2 * i]);
    unsigned short hb = __builtin_bit_cast(unsigned short, (f16)cbf[2 * i + 1]);
    cpk[i] = ((unsigned int)hb << 16) | (unsigned int)lb;
  }

  __syncthreads();   // all waves done reading A1h/A1l (Qs aliases A1h)

  // ---- quantize -> Qs (aliases A1h): id = 8b3+4b2+2b1+b0 ----
  f16 (*Qs)[APITCH] = A1h;
  #pragma unroll
  for (int rr = 0; rr < 16; ++rr) {
    float y = accH[rr] + accL[rr];
    int row = 4 * kg + (rr & 3) + 8 * (rr >> 2);
    int kk = 32 * wv + lrow;
    bool b3 = y > M[7];
    float m2 = b3 ? M[11] : M[3];
    bool b2 = y > m2;
    float m1 = b3 ? (b2 ? M[13] : M[9]) : (b2 ? M[5] : M[1]);
    bool b1 = y > m1;
    float m0 = b1 ? (b3 ? (b2 ? M[14] : M[10]) : (b2 ? M[6] : M[2]))
                  : (b3 ? (b2 ? M[12] : M[8]) : (b2 ? M[4] : M[0]));
    bool b0 = y > m0;
    unsigned int pp = b3 ? (b2 ? (b1 ? cpk[7] : cpk[6]) : (b1 ? cpk[5] : cpk[4]))
                         : (b2 ? (b1 ? cpk[3] : cpk[2]) : (b1 ? cpk[1] : cpk[0]));
    unsigned short qb = (unsigned short)(b0 ? (pp >> 16) : (pp & 0xFFFFu));
    Qs[row][kk] = __builtin_bit_cast(f16, qb);
  }
  __syncthreads();

  // ---- mm2: depth-4 rotation, 2 acc chains, no barriers ----
  f32x16 acc2a = zv, acc2b = zv;
  #pragma unroll
  for (int ks = 0; ks < 16; ks += 4) {
    {
      f16x8 qa = *(const f16x8*)&Qs[lrow][ks * 16 + kg * 8];
      acc2a = __builtin_amdgcn_mfma_f32_32x32x16_f16(qa, c0, acc2a, 0, 0, 0);
      c0 = *(const f16x8*)(W2p + (ks + 4) * 512);     // ks=12 -> pad region
    }
    {
      f16x8 qa = *(const f16x8*)&Qs[lrow][(ks + 1) * 16 + kg * 8];
      acc2b = __builtin_amdgcn_mfma_f32_32x32x16_f16(qa, c1, acc2b, 0, 0, 0);
      c1 = *(const f16x8*)(W2p + (ks + 5) * 512);
    }
    {
      f16x8 qa = *(const f16x8*)&Qs[lrow][(ks + 2) * 16 + kg * 8];
      acc2a = __builtin_amdgcn_mfma_f32_32x32x16_f16(qa, c2, acc2a, 0, 0, 0);
      c2 = *(const f16x8*)(W2p + (ks + 6) * 512);
    }
    {
      f16x8 qa = *(const f16x8*)&Qs[lrow][(ks + 3) * 16 + kg * 8];
      acc2b = __builtin_amdgcn_mfma_f32_32x32x16_f16(qa, c3, acc2b, 0, 0, 0);
      c3 = *(const f16x8*)(W2p + (ks + 7) * 512);
    }
  }

  // ---- epilogue ----
  #pragma unroll
  for (int rr = 0; rr < 16; ++rr) {
    int row = 4 * kg + (rr & 3) + 8 * (rr >> 2);
    int col = 32 * wv + lrow;
    OUT[(row0 + row) * 256 + col] = (acc2a[rr] + acc2b[rr]) * s2s[row];
  }
}

// ============================================================================
// fallback (round-4 kernel, passed at 36 us) if ws is too small
// ============================================================================
#define FB_APITCH 264
#define FB_B1PITCH 40
#define FB_B2PITCH 264

__global__ __launch_bounds__(256, 1) void tq_main_fb(
    const float* __restrict__ X, const float* __restrict__ R,
    const float* __restrict__ CB, float* __restrict__ OUT) {
  __shared__ f16 A1h[64][FB_APITCH];
  __shared__ f16 A1l[64][FB_APITCH];
  __shared__ f16 Qs[64][FB_APITCH];
  __shared__ f32x4 Braw[2624];
  __shared__ float pn[4][64];
  __shared__ float s1s[64];
  __shared__ float s2s[64];

  f16 (*B1h)[FB_B1PITCH] = (f16(*)[FB_B1PITCH])Braw;
  f16 (*B1l)[FB_B1PITCH] = (f16(*)[FB_B1PITCH])((char*)Braw + 20480);
  f16 (*B2h)[FB_B2PITCH] = (f16(*)[FB_B2PITCH])Braw;

  const int tid = threadIdx.x;
  const int lane = tid & 63;
  const int wv = tid >> 6;
  const int lrow = lane & 31;
  const int kg = lane >> 5;
  const long row0 = (long)blockIdx.x * 64;

  float cbf[16];
  #pragma unroll
  for (int i = 0; i < 16; ++i) cbf[i] = CB[i];
  float M[15];
  #pragma unroll
  for (int t = 0; t < 15; ++t) M[t] = 65536.0f * (0.5f * (cbf[t] + cbf[t + 1]));
  unsigned int cpk[8];
  #pragma unroll
  for (int i = 0; i < 8; ++i) {
    unsigned short lb = __builtin_bit_cast(unsigned short, (f16)cbf[2 * i]);
    unsigned short hb = __builtin_bit_cast(unsigned short, (f16)cbf[2 * i + 1]);
    cpk[i] = ((unsigned int)hb << 16) | (unsigned int)lb;
  }

  const int xrow = tid >> 2, xq = tid & 3;
  const float* xp = X + (row0 + xrow) * 256 + xq * 64;
  float xa[64];
  #pragma unroll
  for (int i = 0; i < 16; ++i) {
    f32x4 v = ((const f32x4*)xp)[i];
    xa[4 * i] = v.x; xa[4 * i + 1] = v.y; xa[4 * i + 2] = v.z; xa[4 * i + 3] = v.w;
  }
  float ss = 0.f;
  #pragma unroll
  for (int i = 0; i < 64; ++i) ss += xa[i] * xa[i];
  pn[xq][xrow] = ss;
  __syncthreads();
  if (tid < 64) {
    float s = pn[0][tid] + pn[1][tid] + pn[2][tid] + pn[3][tid];
    float nrm = fmaxf(sqrtf(s), 1e-8f);
    s1s[tid] = 4096.0f / nrm;
    s2s[tid] = nrm * 0.0625f;
  }
  __syncthreads();

  {
    float s1f = s1s[xrow];
    #pragma unroll
    for (int c8 = 0; c8 < 8; ++c8) {
      f16x8 h, l;
      #pragma unroll
      for (int j = 0; j < 8; ++j) {
        float a = xa[c8 * 8 + j] * s1f;
        f16 hh = (f16)a;
        h[j] = hh;
        l[j] = (f16)(a - (float)hh);
      }
      *(f16x8*)&A1h[xrow][xq * 64 + c8 * 8] = h;
      *(f16x8*)&A1l[xrow][xq * 64 + c8 * 8] = l;
    }
  }

  f32x4 pf[8];
  #pragma unroll
  for (int q = 0; q < 8; ++q) {
    int c = q * 256 + tid;
    pf[q] = *(const f32x4*)&R[(long)(c >> 3) * 256 + ((c & 7) * 4)];
  }

  f32x16 zv;
  #pragma unroll
  for (int i = 0; i < 16; ++i) zv[i] = 0.0f;
  f32x16 acc[2][2];
  acc[0][0] = zv; acc[0][1] = zv; acc[1][0] = zv; acc[1][1] = zv;

  for (int kp = 0; kp < 8; ++kp) {
    __syncthreads();
    #pragma unroll
    for (int q = 0; q < 8; ++q) {
      int c = q * 256 + tid;
      int n = c >> 3, k4 = (c & 7) * 4;
      f16x4 h, l;
      #pragma unroll
      for (int j = 0; j < 4; ++j) {
        float sv = pf[q][j] * 256.0f;
        f16 hh = (f16)sv;
        h[j] = hh;
        l[j] = (f16)(sv - (float)hh);
      }
      *(f16x4*)&B1h[n][k4] = h;
      *(f16x4*)&B1l[n][k4] = l;
    }
    __syncthreads();
    if (kp < 7) {
      #pragma unroll
      for (int q = 0; q < 8; ++q) {
        int c = q * 256 + tid;
        pf[q] = *(const f32x4*)&R[(long)(c >> 3) * 256 + (kp + 1) * 32 + ((c & 7) * 4)];
      }
    }
    #pragma unroll
    for (int ks = 0; ks < 2; ++ks) {
      const int k0 = kp * 32 + ks * 16 + kg * 8;
      const int lk = ks * 16 + kg * 8;
      f16x8 ah[2], al[2], bhf[2], blf[2];
      #pragma unroll
      for (int m = 0; m < 2; ++m) {
        ah[m] = *(const f16x8*)&A1h[32 * m + lrow][k0];
        al[m] = *(const f16x8*)&A1l[32 * m + lrow][k0];
      }
      #pragma unroll
      for (int n = 0; n < 2; ++n) {
        int col = 64 * wv + 32 * n + lrow;
        bhf[n] = *(const f16x8*)&B1h[col][lk];
        blf[n] = *(const f16x8*)&B1l[col][lk];
      }
      #pragma unroll
      for (int m = 0; m < 2; ++m)
        #pragma unroll
        for (int n = 0; n < 2; ++n) {
          acc[m][n] = __builtin_amdgcn_mfma_f32_32x32x16_f16(ah[m], bhf[n], acc[m][n], 0, 0, 0);
          acc[m][n] = __builtin_amdgcn_mfma_f32_32x32x16_f16(al[m], bhf[n], acc[m][n], 0, 0, 0);
          acc[m][n] = __builtin_amdgcn_mfma_f32_32x32x16_f16(ah[m], blf[n], acc[m][n], 0, 0, 0);
          acc[m][n] = __builtin_amdgcn_mfma_f32_32x32x16_f16(al[m], blf[n], acc[m][n], 0, 0, 0);
        }
    }
  }

  #pragma unroll
  for (int q = 0; q < 8; ++q) {
    int c = q * 256 + tid;
    pf[q] = *(const f32x4*)&R[(long)(c >> 6) * 256 + ((c & 63) * 4)];
  }

  #pragma unroll
  for (int m = 0; m < 2; ++m)
    #pragma unroll
    for (int n = 0; n < 2; ++n)
      #pragma unroll
      for (int rr = 0; rr < 16; ++rr) {
        float y = acc[m][n][rr];
        int row = 32 * m + 4 * kg + (rr & 3) + 8 * (rr >> 2);
        int kk = 64 * wv + 32 * n + lrow;
        bool b3 = y > M[7];
        float m2 = b3 ? M[11] : M[3];
        bool b2 = y > m2;
        float m1 = b3 ? (b2 ? M[13] : M[9]) : (b2 ? M[5] : M[1]);
        bool b1 = y > m1;
        float m0 = b1 ? (b3 ? (b2 ? M[14] : M[10]) : (b2 ? M[6] : M[2]))
                      : (b3 ? (b2 ? M[12] : M[8]) : (b2 ? M[4] : M[0]));
        bool b0 = y > m0;
        unsigned int pp = b3 ? (b2 ? (b1 ? cpk[7] : cpk[6]) : (b1 ? cpk[5] : cpk[4]))
                             : (b2 ? (b1 ? cpk[3] : cpk[2]) : (b1 ? cpk[1] : cpk[0]));
        unsigned short qb = (unsigned short)(b0 ? (pp >> 16) : (pp & 0xFFFFu));
        Qs[row][kk] = __builtin_bit_cast(f16, qb);
      }
  __syncthreads();

  f32x16 acc2[2][2];
  acc2[0][0] = zv; acc2[0][1] = zv; acc2[1][0] = zv; acc2[1][1] = zv;

  for (int kp = 0; kp < 8; ++kp) {
    if (kp) __syncthreads();
    #pragma unroll
    for (int q = 0; q < 8; ++q) {
      int c = q * 256 + tid;
      int k = c >> 6, n4 = (c & 63) * 4;
      f16x4 h;
      #pragma unroll
      for (int j = 0; j < 4; ++j) h[j] = (f16)pf[q][j];
      *(f16x4*)&B2h[k][n4] = h;
    }
    __syncthreads();
    if (kp < 7) {
      #pragma unroll
      for (int q = 0; q < 8; ++q) {
        int c = q * 256 + tid;
        pf[q] = *(const f32x4*)&R[(long)((kp + 1) * 32 + (c >> 6)) * 256 + ((c & 63) * 4)];
      }
    }
    #pragma unroll
    for (int ks = 0; ks < 2; ++ks) {
      const int k0 = kp * 32 + ks * 16 + kg * 8;
      const int lk = ks * 16 + kg * 8;
      f16x8 qa[2], bb[2];
      #pragma unroll
      for (int m = 0; m < 2; ++m) qa[m] = *(const f16x8*)&Qs[32 * m + lrow][k0];
      #pragma unroll
      for (int n = 0; n < 2; ++n) {
        int colg = 64 * wv + 32 * n + lrow;
        #pragma unroll
        for (int j = 0; j < 8; ++j) bb[n][j] = B2h[lk + j][colg];
      }
      #pragma unroll
      for (int m = 0; m < 2; ++m)
        #pragma unroll
        for (int n = 0; n < 2; ++n)
          acc2[m][n] = __builtin_amdgcn_mfma_f32_32x32x16_f16(qa[m], bb[n], acc2[m][n], 0, 0, 0);
    }
  }

  #pragma unroll
  for (int m = 0; m < 2; ++m)
    #pragma unroll
    for (int n = 0; n < 2; ++n)
      #pragma unroll
      for (int rr = 0; rr < 16; ++rr) {
        int row = 32 * m + 4 * kg + (rr & 3) + 8 * (rr >> 2);
        int col = 64 * wv + 32 * n + lrow;
        OUT[(row0 + row) * 256 + col] = acc2[m][n][rr] * s2s[row];
      }
}

extern "C" void kernel_launch(void* const* d_in, const int* in_sizes, int n_in,
                              void* d_out, int out_size, void* d_ws, size_t ws_size,
                              hipStream_t stream) {
  const float* X = (const float*)d_in[0];
  const float* R = (const float*)d_in[1];
  const float* CB = (const float*)d_in[2];
  float* OUT = (float*)d_out;
  const int nrows = in_sizes[0] / 256;  // 16384

  if (ws_size >= (size_t)3 * WREG * sizeof(f16)) {
    f16* ws = (f16*)d_ws;
    prep_kernel<<<32, 512, 0, stream>>>(R, ws);
    tq_main<<<nrows / 32, 512, 0, stream>>>(X, CB, ws, OUT);
  } else {
    tq_main_fb<<<nrows / 64, 256, 0, stream>>>(X, R, CB, OUT);
  }
}

// Round 9
// 25.142 us; speedup vs baseline: 1.2472x; 1.0387x over previous
//
#include <hip/hip_runtime.h>

typedef _Float16 f16;
typedef _Float16 f16x4 __attribute__((ext_vector_type(4)));
typedef _Float16 f16x8 __attribute__((ext_vector_type(8)));
typedef float f32x16 __attribute__((ext_vector_type(16)));
typedef float f32x4 __attribute__((ext_vector_type(4)));

#define APITCH 264       // f16 units; 528 B pitch
#define WREG 67584       // f16 units per ws region: 65536 + 2048 pad (OOB prefetch)

// ============================================================================
// prep: build fragment-major f16 B-operands in ws. Fragment spec:
//   W1h/W1l[f*512 + l*8 + j] = f16 hi/lo of 256*R[32g + (l&31)][16*ks16 + 8*(l>>5) + j]
//   W2h    [f*512 + l*8 + j] = f16 of        R[16*ks16 + 8*(l>>5) + j][32g + (l&31)]
// 32 blocks: block (g = b>>2, h = b&3) stages panel g (rows 32g..32g+31),
// writes W1 frags f_loc in {4h..4h+3} and W2 frags for gp in {2h, 2h+1}.
// ============================================================================
__global__ __launch_bounds__(512) void prep_kernel(const float* __restrict__ R,
                                                   f16* __restrict__ ws) {
  __shared__ float Lrs[32][260];
  const int b = blockIdx.x;   // 0..31
  const int g = b >> 2, h = b & 3;
  const int t = threadIdx.x;  // 0..511
  f16* W1h = ws;
  f16* W1l = ws + WREG;
  f16* W2h = ws + 2 * WREG;

  #pragma unroll
  for (int it = 0; it < 4; ++it) {
    int c = it * 512 + t;             // 0..2047
    int row = c >> 6, c4 = (c & 63) * 4;
    f32x4 v = *(const f32x4*)&R[(long)(32 * g + row) * 256 + c4];
    *(f32x4*)&Lrs[row][c4] = v;
  }
  __syncthreads();

  if (t < 256) {
    int f_loc = 4 * h + (t >> 6), l = t & 63;
    int k0 = 16 * f_loc + 8 * (l >> 5);
    const float* src = &Lrs[l & 31][k0];
    f16x8 hi, lo;
    #pragma unroll
    for (int j = 0; j < 8; ++j) {
      float v = src[j] * 256.0f;
      f16 hh = (f16)v;
      hi[j] = hh;
      lo[j] = (f16)(v - (float)hh);
    }
    long o = (long)(g * 16 + f_loc) * 512 + l * 8;
    *(f16x8*)(W1h + o) = hi;
    *(f16x8*)(W1l + o) = lo;
  } else {
    int u = t - 256;
    int gp = 2 * h + (u >> 7), e = (u >> 6) & 1, l = u & 63;
    int lr0 = 16 * e + 8 * (l >> 5);
    int col = 32 * gp + (l & 31);
    f16x8 hv;
    #pragma unroll
    for (int j = 0; j < 8; ++j) hv[j] = (f16)Lrs[lr0 + j][col];
    long o = (long)(gp * 16 + 2 * g + e) * 512 + l * 8;
    *(f16x8*)(W2h + o) = hv;
  }
}

// ============================================================================
// main: 512 blocks x 512 threads (8 waves), 32 rows/block, wave tile 32x32.
// mm1 depth-4 B prefetch issued at kernel top (cold latency hides under
// X-load/norm/split). Qs in its own LDS region -> only 2 barriers total.
// ============================================================================
__global__ __launch_bounds__(512, 4) void tq_main(
    const float* __restrict__ X, const float* __restrict__ CB,
    const f16* __restrict__ ws, float* __restrict__ OUT) {
  __shared__ f16 A1h[32][APITCH];
  __shared__ f16 A1l[32][APITCH];
  __shared__ f16 Qs[32][APITCH];
  __shared__ float s2s[32];

  const int tid = threadIdx.x;
  const int lane = tid & 63;
  const int wv = tid >> 6;       // 0..7 = 32-col group
  const int lrow = lane & 31;
  const int kg = lane >> 5;
  const long row0 = (long)blockIdx.x * 32;

  const f16* W1h = ws;
  const f16* W1l = ws + WREG;
  const f16* W2h = ws + 2 * WREG;

  // ---- issue x loads first (HBM critical path) ----
  const int r = tid >> 4, q = tid & 15;
  const float* xp = X + (row0 + r) * 256 + q * 16;
  float xa[16];
  #pragma unroll
  for (int i = 0; i < 4; ++i) {
    f32x4 v = ((const f32x4*)xp)[i];
    xa[4 * i] = v.x; xa[4 * i + 1] = v.y; xa[4 * i + 2] = v.z; xa[4 * i + 3] = v.w;
  }

  // ---- issue mm1 depth-4 B preloads NOW (cold miss hides under norm/split) ----
  const f16* W1hp = W1h + (long)(wv * 16) * 512 + lane * 8;
  const f16* W1lp = W1l + (long)(wv * 16) * 512 + lane * 8;
  f16x8 bh0 = *(const f16x8*)(W1hp);
  f16x8 bl0 = *(const f16x8*)(W1lp);
  f16x8 bh1 = *(const f16x8*)(W1hp + 512);
  f16x8 bl1 = *(const f16x8*)(W1lp + 512);
  f16x8 bh2 = *(const f16x8*)(W1hp + 1024);
  f16x8 bl2 = *(const f16x8*)(W1lp + 1024);
  f16x8 bh3 = *(const f16x8*)(W1hp + 1536);
  f16x8 bl3 = *(const f16x8*)(W1lp + 1536);

  // ---- codebook load issued early ----
  float cbf[16];
  #pragma unroll
  for (int i = 0; i < 16; ++i) cbf[i] = CB[i];

  // ---- wave-local norm via shfl (16 threads/row) ----
  float ss = 0.f;
  #pragma unroll
  for (int i = 0; i < 16; ++i) ss += xa[i] * xa[i];
  ss += __shfl_xor(ss, 8, 16);
  ss += __shfl_xor(ss, 4, 16);
  ss += __shfl_xor(ss, 2, 16);
  ss += __shfl_xor(ss, 1, 16);
  float nrm = fmaxf(sqrtf(ss), 1e-8f);
  float s1f = 4096.0f / nrm;         // y_raw = 65536 * y_scaled
  if (q == 0) s2s[r] = nrm * 0.0625f;

  // ---- split A = x*s1 into f16 hi/lo -> LDS ----
  #pragma unroll
  for (int c8 = 0; c8 < 2; ++c8) {
    f16x8 h, l;
    #pragma unroll
    for (int j = 0; j < 8; ++j) {
      float a = xa[c8 * 8 + j] * s1f;
      f16 hh = (f16)a;
      h[j] = hh;
      l[j] = (f16)(a - (float)hh);
    }
    *(f16x8*)&A1h[r][q * 16 + c8 * 8] = h;
    *(f16x8*)&A1l[r][q * 16 + c8 * 8] = l;
  }
  __syncthreads();

  // ---- mm1: depth-4 prefetch, dual acc chains, 3-term split, no barriers ----
  f32x16 zv;
  #pragma unroll
  for (int i = 0; i < 16; ++i) zv[i] = 0.0f;
  f32x16 accH = zv, accL = zv;

#define MM1_STAGE(BH, BL, KS)                                                   \
  {                                                                             \
    const int k0 = (KS) * 16 + kg * 8;                                          \
    f16x8 ah = *(const f16x8*)&A1h[lrow][k0];                                   \
    f16x8 al = *(const f16x8*)&A1l[lrow][k0];                                   \
    accH = __builtin_amdgcn_mfma_f32_32x32x16_f16(ah, BH, accH, 0, 0, 0);       \
    accL = __builtin_amdgcn_mfma_f32_32x32x16_f16(al, BH, accL, 0, 0, 0);       \
    accH = __builtin_amdgcn_mfma_f32_32x32x16_f16(ah, BL, accH, 0, 0, 0);       \
    BH = *(const f16x8*)(W1hp + ((KS) + 4) * 512);                              \
    BL = *(const f16x8*)(W1lp + ((KS) + 4) * 512);                              \
  }

  #pragma unroll
  for (int ksb = 0; ksb < 16; ksb += 4) {
    MM1_STAGE(bh0, bl0, ksb)
    MM1_STAGE(bh1, bl1, ksb + 1)
    MM1_STAGE(bh2, bl2, ksb + 2)
    MM1_STAGE(bh3, bl3, ksb + 3)
  }
#undef MM1_STAGE

  // ---- issue mm2 depth-4 preloads (latency hides under quantize) ----
  const f16* W2p = W2h + (long)(wv * 16) * 512 + lane * 8;
  f16x8 c0 = *(const f16x8*)(W2p);
  f16x8 c1 = *(const f16x8*)(W2p + 512);
  f16x8 c2 = *(const f16x8*)(W2p + 1024);
  f16x8 c3 = *(const f16x8*)(W2p + 1536);

  // ---- midpoints / packed codebook ----
  float M[15];
  #pragma unroll
  for (int t = 0; t < 15; ++t) M[t] = 65536.0f * (0.5f * (cbf[t] + cbf[t + 1]));
  unsigned int cpk[8];
  #pragma unroll
  for (int i = 0; i < 8; ++i) {
    unsigned short lb = __builtin_bit_cast(unsigned short, (f16)cbf[2 * i]);
    unsigned short hb = __builtin_bit_cast(unsigned short, (f16)cbf[2 * i + 1]);
    cpk[i] = ((unsigned int)hb << 16) | (unsigned int)lb;
  }

  // ---- quantize -> Qs (own region, no barrier needed before writes) ----
  #pragma unroll
  for (int rr = 0; rr < 16; ++rr) {
    float y = accH[rr] + accL[rr];
    int row = 4 * kg + (rr & 3) + 8 * (rr >> 2);
    int kk = 32 * wv + lrow;
    bool b3 = y > M[7];
    float m2 = b3 ? M[11] : M[3];
    bool b2 = y > m2;
    float m1 = b3 ? (b2 ? M[13] : M[9]) : (b2 ? M[5] : M[1]);
    bool b1 = y > m1;
    float m0 = b1 ? (b3 ? (b2 ? M[14] : M[10]) : (b2 ? M[6] : M[2]))
                  : (b3 ? (b2 ? M[12] : M[8]) : (b2 ? M[4] : M[0]));
    bool b0 = y > m0;
    unsigned int pp = b3 ? (b2 ? (b1 ? cpk[7] : cpk[6]) : (b1 ? cpk[5] : cpk[4]))
                         : (b2 ? (b1 ? cpk[3] : cpk[2]) : (b1 ? cpk[1] : cpk[0]));
    unsigned short qb = (unsigned short)(b0 ? (pp >> 16) : (pp & 0xFFFFu));
    Qs[row][kk] = __builtin_bit_cast(f16, qb);
  }
  __syncthreads();   // all Qs writes visible before mm2 reads

  // ---- mm2: depth-4 rotation, 2 acc chains, no barriers ----
  f32x16 acc2a = zv, acc2b = zv;
  #pragma unroll
  for (int ks = 0; ks < 16; ks += 4) {
    {
      f16x8 qa = *(const f16x8*)&Qs[lrow][ks * 16 + kg * 8];
      acc2a = __builtin_amdgcn_mfma_f32_32x32x16_f16(qa, c0, acc2a, 0, 0, 0);
      c0 = *(const f16x8*)(W2p + (ks + 4) * 512);     // ks=12 -> pad region
    }
    {
      f16x8 qa = *(const f16x8*)&Qs[lrow][(ks + 1) * 16 + kg * 8];
      acc2b = __builtin_amdgcn_mfma_f32_32x32x16_f16(qa, c1, acc2b, 0, 0, 0);
      c1 = *(const f16x8*)(W2p + (ks + 5) * 512);
    }
    {
      f16x8 qa = *(const f16x8*)&Qs[lrow][(ks + 2) * 16 + kg * 8];
      acc2a = __builtin_amdgcn_mfma_f32_32x32x16_f16(qa, c2, acc2a, 0, 0, 0);
      c2 = *(const f16x8*)(W2p + (ks + 6) * 512);
    }
    {
      f16x8 qa = *(const f16x8*)&Qs[lrow][(ks + 3) * 16 + kg * 8];
      acc2b = __builtin_amdgcn_mfma_f32_32x32x16_f16(qa, c3, acc2b, 0, 0, 0);
      c3 = *(const f16x8*)(W2p + (ks + 7) * 512);
    }
  }

  // ---- epilogue ----
  #pragma unroll
  for (int rr = 0; rr < 16; ++rr) {
    int row = 4 * kg + (rr & 3) + 8 * (rr >> 2);
    int col = 32 * wv + lrow;
    OUT[(row0 + row) * 256 + col] = (acc2a[rr] + acc2b[rr]) * s2s[row];
  }
}

// ============================================================================
// fallback (round-4 kernel, passed at 36 us) if ws is too small
// ============================================================================
#define FB_APITCH 264
#define FB_B1PITCH 40
#define FB_B2PITCH 264

__global__ __launch_bounds__(256, 1) void tq_main_fb(
    const float* __restrict__ X, const float* __restrict__ R,
    const float* __restrict__ CB, float* __restrict__ OUT) {
  __shared__ f16 A1h[64][FB_APITCH];
  __shared__ f16 A1l[64][FB_APITCH];
  __shared__ f16 Qs[64][FB_APITCH];
  __shared__ f32x4 Braw[2624];
  __shared__ float pn[4][64];
  __shared__ float s1s[64];
  __shared__ float s2s[64];

  f16 (*B1h)[FB_B1PITCH] = (f16(*)[FB_B1PITCH])Braw;
  f16 (*B1l)[FB_B1PITCH] = (f16(*)[FB_B1PITCH])((char*)Braw + 20480);
  f16 (*B2h)[FB_B2PITCH] = (f16(*)[FB_B2PITCH])Braw;

  const int tid = threadIdx.x;
  const int lane = tid & 63;
  const int wv = tid >> 6;
  const int lrow = lane & 31;
  const int kg = lane >> 5;
  const long row0 = (long)blockIdx.x * 64;

  float cbf[16];
  #pragma unroll
  for (int i = 0; i < 16; ++i) cbf[i] = CB[i];
  float M[15];
  #pragma unroll
  for (int t = 0; t < 15; ++t) M[t] = 65536.0f * (0.5f * (cbf[t] + cbf[t + 1]));
  unsigned int cpk[8];
  #pragma unroll
  for (int i = 0; i < 8; ++i) {
    unsigned short lb = __builtin_bit_cast(unsigned short, (f16)cbf[2 * i]);
    unsigned short hb = __builtin_bit_cast(unsigned short, (f16)cbf[2 * i + 1]);
    cpk[i] = ((unsigned int)hb << 16) | (unsigned int)lb;
  }

  const int xrow = tid >> 2, xq = tid & 3;
  const float* xp = X + (row0 + xrow) * 256 + xq * 64;
  float xa[64];
  #pragma unroll
  for (int i = 0; i < 16; ++i) {
    f32x4 v = ((const f32x4*)xp)[i];
    xa[4 * i] = v.x; xa[4 * i + 1] = v.y; xa[4 * i + 2] = v.z; xa[4 * i + 3] = v.w;
  }
  float ss = 0.f;
  #pragma unroll
  for (int i = 0; i < 64; ++i) ss += xa[i] * xa[i];
  pn[xq][xrow] = ss;
  __syncthreads();
  if (tid < 64) {
    float s = pn[0][tid] + pn[1][tid] + pn[2][tid] + pn[3][tid];
    float nrm = fmaxf(sqrtf(s), 1e-8f);
    s1s[tid] = 4096.0f / nrm;
    s2s[tid] = nrm * 0.0625f;
  }
  __syncthreads();

  {
    float s1f = s1s[xrow];
    #pragma unroll
    for (int c8 = 0; c8 < 8; ++c8) {
      f16x8 h, l;
      #pragma unroll
      for (int j = 0; j < 8; ++j) {
        float a = xa[c8 * 8 + j] * s1f;
        f16 hh = (f16)a;
        h[j] = hh;
        l[j] = (f16)(a - (float)hh);
      }
      *(f16x8*)&A1h[xrow][xq * 64 + c8 * 8] = h;
      *(f16x8*)&A1l[xrow][xq * 64 + c8 * 8] = l;
    }
  }

  f32x4 pf[8];
  #pragma unroll
  for (int q = 0; q < 8; ++q) {
    int c = q * 256 + tid;
    pf[q] = *(const f32x4*)&R[(long)(c >> 3) * 256 + ((c & 7) * 4)];
  }

  f32x16 zv;
  #pragma unroll
  for (int i = 0; i < 16; ++i) zv[i] = 0.0f;
  f32x16 acc[2][2];
  acc[0][0] = zv; acc[0][1] = zv; acc[1][0] = zv; acc[1][1] = zv;

  for (int kp = 0; kp < 8; ++kp) {
    __syncthreads();
    #pragma unroll
    for (int q = 0; q < 8; ++q) {
      int c = q * 256 + tid;
      int n = c >> 3, k4 = (c & 7) * 4;
      f16x4 h, l;
      #pragma unroll
      for (int j = 0; j < 4; ++j) {
        float sv = pf[q][j] * 256.0f;
        f16 hh = (f16)sv;
        h[j] = hh;
        l[j] = (f16)(sv - (float)hh);
      }
      *(f16x4*)&B1h[n][k4] = h;
      *(f16x4*)&B1l[n][k4] = l;
    }
    __syncthreads();
    if (kp < 7) {
      #pragma unroll
      for (int q = 0; q < 8; ++q) {
        int c = q * 256 + tid;
        pf[q] = *(const f32x4*)&R[(long)(c >> 3) * 256 + (kp + 1) * 32 + ((c & 7) * 4)];
      }
    }
    #pragma unroll
    for (int ks = 0; ks < 2; ++ks) {
      const int k0 = kp * 32 + ks * 16 + kg * 8;
      const int lk = ks * 16 + kg * 8;
      f16x8 ah[2], al[2], bhf[2], blf[2];
      #pragma unroll
      for (int m = 0; m < 2; ++m) {
        ah[m] = *(const f16x8*)&A1h[32 * m + lrow][k0];
        al[m] = *(const f16x8*)&A1l[32 * m + lrow][k0];
      }
      #pragma unroll
      for (int n = 0; n < 2; ++n) {
        int col = 64 * wv + 32 * n + lrow;
        bhf[n] = *(const f16x8*)&B1h[col][lk];
        blf[n] = *(const f16x8*)&B1l[col][lk];
      }
      #pragma unroll
      for (int m = 0; m < 2; ++m)
        #pragma unroll
        for (int n = 0; n < 2; ++n) {
          acc[m][n] = __builtin_amdgcn_mfma_f32_32x32x16_f16(ah[m], bhf[n], acc[m][n], 0, 0, 0);
          acc[m][n] = __builtin_amdgcn_mfma_f32_32x32x16_f16(al[m], bhf[n], acc[m][n], 0, 0, 0);
          acc[m][n] = __builtin_amdgcn_mfma_f32_32x32x16_f16(ah[m], blf[n], acc[m][n], 0, 0, 0);
          acc[m][n] = __builtin_amdgcn_mfma_f32_32x32x16_f16(al[m], blf[n], acc[m][n], 0, 0, 0);
        }
    }
  }

  #pragma unroll
  for (int q = 0; q < 8; ++q) {
    int c = q * 256 + tid;
    pf[q] = *(const f32x4*)&R[(long)(c >> 6) * 256 + ((c & 63) * 4)];
  }

  #pragma unroll
  for (int m = 0; m < 2; ++m)
    #pragma unroll
    for (int n = 0; n < 2; ++n)
      #pragma unroll
      for (int rr = 0; rr < 16; ++rr) {
        float y = acc[m][n][rr];
        int row = 32 * m + 4 * kg + (rr & 3) + 8 * (rr >> 2);
        int kk = 64 * wv + 32 * n + lrow;
        bool b3 = y > M[7];
        float m2 = b3 ? M[11] : M[3];
        bool b2 = y > m2;
        float m1 = b3 ? (b2 ? M[13] : M[9]) : (b2 ? M[5] : M[1]);
        bool b1 = y > m1;
        float m0 = b1 ? (b3 ? (b2 ? M[14] : M[10]) : (b2 ? M[6] : M[2]))
                      : (b3 ? (b2 ? M[12] : M[8]) : (b2 ? M[4] : M[0]));
        bool b0 = y > m0;
        unsigned int pp = b3 ? (b2 ? (b1 ? cpk[7] : cpk[6]) : (b1 ? cpk[5] : cpk[4]))
                             : (b2 ? (b1 ? cpk[3] : cpk[2]) : (b1 ? cpk[1] : cpk[0]));
        unsigned short qb = (unsigned short)(b0 ? (pp >> 16) : (pp & 0xFFFFu));
        Qs[row][kk] = __builtin_bit_cast(f16, qb);
      }
  __syncthreads();

  f32x16 acc2[2][2];
  acc2[0][0] = zv; acc2[0][1] = zv; acc2[1][0] = zv; acc2[1][1] = zv;

  for (int kp = 0; kp < 8; ++kp) {
    if (kp) __syncthreads();
    #pragma unroll
    for (int q = 0; q < 8; ++q) {
      int c = q * 256 + tid;
      int k = c >> 6, n4 = (c & 63) * 4;
      f16x4 h;
      #pragma unroll
      for (int j = 0; j < 4; ++j) h[j] = (f16)pf[q][j];
      *(f16x4*)&B2h[k][n4] = h;
    }
    __syncthreads();
    if (kp < 7) {
      #pragma unroll
      for (int q = 0; q < 8; ++q) {
        int c = q * 256 + tid;
        pf[q] = *(const f32x4*)&R[(long)((kp + 1) * 32 + (c >> 6)) * 256 + ((c & 63) * 4)];
      }
    }
    #pragma unroll
    for (int ks = 0; ks < 2; ++ks) {
      const int k0 = kp * 32 + ks * 16 + kg * 8;
      const int lk = ks * 16 + kg * 8;
      f16x8 qa[2], bb[2];
      #pragma unroll
      for (int m = 0; m < 2; ++m) qa[m] = *(const f16x8*)&Qs[32 * m + lrow][k0];
      #pragma unroll
      for (int n = 0; n < 2; ++n) {
        int colg = 64 * wv + 32 * n + lrow;
        #pragma unroll
        for (int j = 0; j < 8; ++j) bb[n][j] = B2h[lk + j][colg];
      }
      #pragma unroll
      for (int m = 0; m < 2; ++m)
        #pragma unroll
        for (int n = 0; n < 2; ++n)
          acc2[m][n] = __builtin_amdgcn_mfma_f32_32x32x16_f16(qa[m], bb[n], acc2[m][n], 0, 0, 0);
    }
  }

  #pragma unroll
  for (int m = 0; m < 2; ++m)
    #pragma unroll
    for (int n = 0; n < 2; ++n)
      #pragma unroll
      for (int rr = 0; rr < 16; ++rr) {
        int row = 32 * m + 4 * kg + (rr & 3) + 8 * (rr >> 2);
        int col = 64 * wv + 32 * n + lrow;
        OUT[(row0 + row) * 256 + col] = acc2[m][n][rr] * s2s[row];
      }
}

extern "C" void kernel_launch(void* const* d_in, const int* in_sizes, int n_in,
                              void* d_out, int out_size, void* d_ws, size_t ws_size,
                              hipStream_t stream) {
  const float* X = (const float*)d_in[0];
  const float* R = (const float*)d_in[1];
  const float* CB = (const float*)d_in[2];
  float* OUT = (float*)d_out;
  const int nrows = in_sizes[0] / 256;  // 16384

  if (ws_size >= (size_t)3 * WREG * sizeof(f16)) {
    f16* ws = (f16*)d_ws;
    prep_kernel<<<32, 512, 0, stream>>>(R, ws);
    tq_main<<<nrows / 32, 512, 0, stream>>>(X, CB, ws, OUT);
  } else {
    tq_main_fb<<<nrows / 64, 256, 0, stream>>>(X, R, CB, OUT);
  }
}